// Round 2
// baseline (860.065 us; speedup 1.0000x reference)
//
#include <hip/hip_runtime.h>
#include <hip/hip_bf16.h>

// Shifted-window attention (Swin), B=32 H=W=56 C=256 NH=8 hd=32 WS=7 SHIFT=3.
// Inputs/outputs are fp32 (reference dtype). MFMA compute in bf16.
// Kernel 1: convert qkvW/projW fp32->bf16 into d_ws.
// Kernel 2: one workgroup (256 thr = 4 waves) per window; 2048 windows.

#define NTOK 49      // 7*7 tokens per window
#define DIM_ 256
#define NH_  8
#define HD_  32
#define NQKV 196608  // 768*256
#define NPRJ 65536   // 256*256

typedef short v8s __attribute__((ext_vector_type(8)));
typedef float v4f __attribute__((ext_vector_type(4)));

static __device__ __forceinline__ v8s zero_v8s() {
    v8s z = {0, 0, 0, 0, 0, 0, 0, 0};
    return z;
}

// Guarded 16B fragment load from an LDS bf16 array (row-major, element stride).
static __device__ __forceinline__ v8s load_frag(const __hip_bfloat16* p, int row,
                                                int stride, int koff, int nrows) {
    if (row < nrows) return *(const v8s*)(p + row * stride + koff);
    return zero_v8s();
}

__global__ __launch_bounds__(256) void convert_weights_kernel(
    const float* __restrict__ qkvW, const float* __restrict__ projW,
    __hip_bfloat16* __restrict__ wsQ, __hip_bfloat16* __restrict__ wsP)
{
    int i = blockIdx.x * 256 + threadIdx.x;
    if (i < NQKV) wsQ[i] = __float2bfloat16(qkvW[i]);
    int j = i - NQKV;
    if (j >= 0 && j < NPRJ) wsP[j] = __float2bfloat16(projW[j]);
}

__global__ __launch_bounds__(256) void swin_attn_kernel(
    const float* __restrict__ x,         // (32,56,56,256)
    const float* __restrict__ qkvB,      // (768,)
    const float* __restrict__ projB,     // (256,)
    const float* __restrict__ rbt,       // (169,8)
    const int*   __restrict__ rpi,       // (2401,)
    const __hip_bfloat16* __restrict__ wsQ,  // (768,256) bf16
    const __hip_bfloat16* __restrict__ wsP,  // (256,256) bf16
    float*       __restrict__ out)       // (32,56,56,256)
{
    constexpr int SXS = 264;  // s_x row stride (elements); 528B = 33*16
    constexpr int QKS = 40;   // q/k row stride; 80B = 5*16
    constexpr int VTS = 72;   // vt row stride; 144B
    constexpr int PS  = 72;   // P row stride
    constexpr int OHS = 40;   // per-head attn-out stride

    __shared__ alignas(16) __hip_bfloat16 s_x[NTOK * SXS];   // window x, bf16 (49x256)
    __shared__ alignas(16) __hip_bfloat16 s_q[NTOK * QKS];   // q (49x32)
    __shared__ alignas(16) __hip_bfloat16 s_k[NTOK * QKS];   // k (49x32)
    __shared__ alignas(16) __hip_bfloat16 s_vt[HD_ * VTS];   // v^T (32x64), cols>=49 zero
    __shared__ alignas(16) __hip_bfloat16 s_p[NTOK * PS];    // softmax P (49x64)
    __shared__ alignas(16) __hip_bfloat16 s_oh[NTOK * OHS];  // per-head attn out (49x32)
    __shared__ int s_off[NTOK];                              // global token offsets (elements)
    __shared__ int s_reg[NTOK];                              // shift-mask region ids

    const int tid  = threadIdx.x;
    const int wave = tid >> 6;
    const int lane = tid & 63;
    const int quad = lane >> 4;
    const int l16  = lane & 15;

    const int wid  = blockIdx.x;       // 0..2047
    const int b    = wid >> 6;
    const int wIdx = wid & 63;
    const int wh   = wIdx >> 3;
    const int wwi  = wIdx & 7;

    // ---- setup: shifted gather offsets + mask region ids ----
    if (tid < NTOK) {
        int r = tid / 7, c = tid % 7;
        int hs = wh * 7 + r;                       // shifted-image coords
        int ws = wwi * 7 + c;
        int hg = hs + 3; if (hg >= 56) hg -= 56;   // source in original x (roll -3)
        int wg = ws + 3; if (wg >= 56) wg -= 56;
        s_off[tid] = ((b * 56 + hg) * 56 + wg) * DIM_;
        int rh = (hs < 49) ? 0 : ((hs < 53) ? 1 : 2);
        int rw = (ws < 49) ? 0 : ((ws < 53) ? 1 : 2);
        s_reg[tid] = rh * 3 + rw;
    }
    // zero vt padding cols [49,64)
    for (int i = tid; i < HD_ * 15; i += 256) {
        int n = i / 15, kk = 49 + (i % 15);
        s_vt[n * VTS + kk] = __float2bfloat16(0.0f);
    }
    __syncthreads();

    // ---- stage window x -> bf16 LDS (once) ----
    for (int i = tid; i < NTOK * 64; i += 256) {
        int t = i >> 6, f4 = (i & 63) * 4;
        const float* src = x + s_off[t] + f4;
        float4 v = *(const float4*)src;
        __hip_bfloat16* dst = s_x + t * SXS + f4;
        dst[0] = __float2bfloat16(v.x);
        dst[1] = __float2bfloat16(v.y);
        dst[2] = __float2bfloat16(v.z);
        dst[3] = __float2bfloat16(v.w);
    }
    __syncthreads();

    const float qscale = 0.17677669529663687f;  // 1/sqrt(32)

    v4f pacc[16];
    for (int nt = 0; nt < 16; ++nt) pacc[nt] = (v4f){0.f, 0.f, 0.f, 0.f};

    for (int h = 0; h < NH_; ++h) {
        // ---- Step A: q,k,v = x_win @ qkvW^T (+bias); 24 16x16 tiles, 6 per wave ----
        for (int t = 0; t < 6; ++t) {
            int id    = wave * 6 + t;
            int mat   = id >> 3;            // 0=q 1=k 2=v
            int mtile = (id >> 1) & 3;
            int ntile = id & 1;
            int m     = mtile * 16 + l16;
            int nout  = mat * 256 + h * 32 + ntile * 16 + l16;
            const __hip_bfloat16* wrow = wsQ + nout * DIM_;
            v4f acc = {0.f, 0.f, 0.f, 0.f};
            for (int ks = 0; ks < 8; ++ks) {
                int koff = ks * 32 + quad * 8;
                v8s a  = load_frag(s_x, m, SXS, koff, NTOK);
                v8s bf = *(const v8s*)(wrow + koff);
                acc = __builtin_amdgcn_mfma_f32_16x16x32_bf16(a, bf, acc, 0, 0, 0);
            }
            float bias  = qkvB[nout];
            float scale = (mat == 0) ? qscale : 1.0f;
            for (int rg = 0; rg < 4; ++rg) {
                int row = mtile * 16 + quad * 4 + rg;
                if (row < NTOK) {
                    float v = (acc[rg] + bias) * scale;
                    int col = ntile * 16 + l16;          // feature within head
                    __hip_bfloat16 bv = __float2bfloat16(v);
                    if (mat == 0)      s_q[row * QKS + col] = bv;
                    else if (mat == 1) s_k[row * QKS + col] = bv;
                    else               s_vt[col * VTS + row] = bv;   // transposed
                }
            }
        }
        __syncthreads();

        // ---- Step B: S = q k^T + bias + mask; softmax -> P (bf16) ----
        {
            int m0 = wave * 16;
            v8s a = load_frag(s_q, m0 + l16, QKS, quad * 8, NTOK);
            v4f accs[4];
            for (int nt = 0; nt < 4; ++nt) {
                v8s bf = load_frag(s_k, nt * 16 + l16, QKS, quad * 8, NTOK);
                v4f z = {0.f, 0.f, 0.f, 0.f};
                accs[nt] = __builtin_amdgcn_mfma_f32_16x16x32_bf16(a, bf, z, 0, 0, 0);
            }
            for (int rg = 0; rg < 4; ++rg) {
                int row = m0 + quad * 4 + rg;   // quad-uniform
                float v[4];
                float rmax = -1e30f;
                for (int nt = 0; nt < 4; ++nt) {
                    int col = nt * 16 + l16;
                    float s;
                    if (row < NTOK && col < NTOK) {
                        s = accs[nt][rg] + rbt[rpi[row * NTOK + col] * NH_ + h];
                        if (s_reg[row] != s_reg[col]) s -= 100.0f;
                    } else {
                        s = -1e30f;
                    }
                    v[nt] = s;
                    rmax = fmaxf(rmax, s);
                }
                for (int mm = 8; mm >= 1; mm >>= 1)
                    rmax = fmaxf(rmax, __shfl_xor(rmax, mm, 64));
                float rsum = 0.f;
                for (int nt = 0; nt < 4; ++nt) {
                    float e = (v[nt] <= -1e29f) ? 0.f : __expf(v[nt] - rmax);
                    v[nt] = e;
                    rsum += e;
                }
                for (int mm = 8; mm >= 1; mm >>= 1)
                    rsum += __shfl_xor(rsum, mm, 64);
                if (row < NTOK) {
                    float inv = 1.0f / rsum;
                    for (int nt = 0; nt < 4; ++nt)
                        s_p[row * PS + nt * 16 + l16] = __float2bfloat16(v[nt] * inv);
                }
            }
        }
        __syncthreads();

        // ---- Step C: oh = P @ v  (49x32) ----
        {
            int m0 = wave * 16;
            for (int nt = 0; nt < 2; ++nt) {
                v4f acc = {0.f, 0.f, 0.f, 0.f};
                for (int ks = 0; ks < 2; ++ks) {
                    v8s a  = load_frag(s_p, m0 + l16, PS, ks * 32 + quad * 8, NTOK);
                    v8s bf = *(const v8s*)(s_vt + (nt * 16 + l16) * VTS + ks * 32 + quad * 8);
                    acc = __builtin_amdgcn_mfma_f32_16x16x32_bf16(a, bf, acc, 0, 0, 0);
                }
                for (int rg = 0; rg < 4; ++rg) {
                    int row = m0 + quad * 4 + rg;
                    if (row < NTOK)
                        s_oh[row * OHS + nt * 16 + l16] = __float2bfloat16(acc[rg]);
                }
            }
        }
        __syncthreads();

        // ---- per-head proj accumulate: pacc += oh @ projW[:, h*32:(h+1)*32]^T ----
        {
            int m0 = wave * 16;
            v8s a = load_frag(s_oh, m0 + l16, OHS, quad * 8, NTOK);
            for (int nt = 0; nt < 16; ++nt) {
                v8s bf = *(const v8s*)(wsP + (nt * 16 + l16) * DIM_ + h * 32 + quad * 8);
                pacc[nt] = __builtin_amdgcn_mfma_f32_16x16x32_bf16(a, bf, pacc[nt], 0, 0, 0);
            }
        }
        // no barrier needed here: next Step C's s_oh write is 2 barriers away
    }

    // ---- add proj bias, scatter fp32 with reverse shift ----
    {
        for (int nt = 0; nt < 16; ++nt) {
            float pb = projB[nt * 16 + l16];
            for (int rg = 0; rg < 4; ++rg) {
                int row = wave * 16 + quad * 4 + rg;
                if (row < NTOK)
                    out[s_off[row] + nt * 16 + l16] = pacc[nt][rg] + pb;
            }
        }
    }
}

extern "C" void kernel_launch(void* const* d_in, const int* in_sizes, int n_in,
                              void* d_out, int out_size, void* d_ws, size_t ws_size,
                              hipStream_t stream) {
    const float* x     = (const float*)d_in[0];
    const float* qkvW  = (const float*)d_in[1];
    const float* qkvB  = (const float*)d_in[2];
    const float* projW = (const float*)d_in[3];
    const float* projB = (const float*)d_in[4];
    const float* rbt   = (const float*)d_in[5];
    const int*   rpi   = (const int*)d_in[6];
    float* o = (float*)d_out;

    __hip_bfloat16* wsQ = (__hip_bfloat16*)d_ws;
    __hip_bfloat16* wsP = wsQ + NQKV;

    convert_weights_kernel<<<(NQKV + NPRJ + 255) / 256, 256, 0, stream>>>(qkvW, projW, wsQ, wsP);
    swin_attn_kernel<<<2048, 256, 0, stream>>>(x, qkvB, projB, rbt, rpi, wsQ, wsP, o);
}

// Round 3
// 683.940 us; speedup vs baseline: 1.2575x; 1.2575x over previous
//
#include <hip/hip_runtime.h>
#include <hip/hip_bf16.h>

// Shifted-window attention (Swin), B=32 H=W=56 C=256 NH=8 hd=32 WS=7 SHIFT=3.
// fp32 in/out; bf16 MFMA compute.
// prep_kernel: qkvW/projW fp32->bf16 in ws + precomputed bias table (8x49x49 fp32).
// swin_attn_kernel: 1 block (4 waves) per window; each wave owns 2 heads
// end-to-end with wave-private LDS (no __syncthreads between heads; wave-lockstep
// + s_waitcnt lgkmcnt(0) handoffs). Only 2 block-wide barriers total.

#define NTOK 49
#define DIM_ 256
#define NH_  8
#define NQKV 196608  // 768*256
#define NPRJ 65536   // 256*256
#define NTAB 19208   // 8*49*49

typedef short v8s __attribute__((ext_vector_type(8)));
typedef float v4f __attribute__((ext_vector_type(4)));

#define MFMA16 __builtin_amdgcn_mfma_f32_16x16x32_bf16
#define LGKM_WAIT() asm volatile("s_waitcnt lgkmcnt(0)" ::: "memory")

static __device__ __forceinline__ v8s zero_v8s() {
    v8s z = {0, 0, 0, 0, 0, 0, 0, 0};
    return z;
}

static __device__ __forceinline__ v8s lds_frag(const __hip_bfloat16* p, int row,
                                               int stride, int koff, int nrows) {
    if (row < nrows) return *(const v8s*)(p + row * stride + koff);
    return zero_v8s();
}

// 8 consecutive fp32 -> 8 bf16 fragment (32B-aligned source)
static __device__ __forceinline__ v8s cvt8(const float* p) {
    v4f a = *(const v4f*)p;
    v4f b = *(const v4f*)(p + 4);
    union { v8s v; __hip_bfloat16 h[8]; } r;
    r.h[0] = __float2bfloat16(a[0]); r.h[1] = __float2bfloat16(a[1]);
    r.h[2] = __float2bfloat16(a[2]); r.h[3] = __float2bfloat16(a[3]);
    r.h[4] = __float2bfloat16(b[0]); r.h[5] = __float2bfloat16(b[1]);
    r.h[6] = __float2bfloat16(b[2]); r.h[7] = __float2bfloat16(b[3]);
    return r.v;
}

__global__ __launch_bounds__(256) void prep_kernel(
    const float* __restrict__ qkvW, const float* __restrict__ projW,
    const float* __restrict__ rbt, const int* __restrict__ rpi,
    __hip_bfloat16* __restrict__ wsQ, __hip_bfloat16* __restrict__ wsP,
    float* __restrict__ tab, int doTab)
{
    int i = blockIdx.x * 256 + threadIdx.x;
    if (i < NQKV) { wsQ[i] = __float2bfloat16(qkvW[i]); return; }
    int j = i - NQKV;
    if (j < NPRJ) { wsP[j] = __float2bfloat16(projW[j]); return; }
    int t = j - NPRJ;
    if (doTab && t < NTAB) {
        int h = t / 2401, p = t - h * 2401;
        tab[t] = rbt[rpi[p] * NH_ + h];
    }
}

__global__ __launch_bounds__(256, 2) void swin_attn_kernel(
    const float* __restrict__ x,         // (32,56,56,256)
    const float* __restrict__ qkvB,      // (768,)
    const float* __restrict__ projB,     // (256,)
    const float* __restrict__ rbt,       // (169,8)
    const int*   __restrict__ rpi,       // (2401,)
    const __hip_bfloat16* __restrict__ wsQ,  // (768,256) bf16
    const __hip_bfloat16* __restrict__ wsP,  // (256,256) bf16
    const float* __restrict__ biasTab,   // (8,49,49) fp32, or nullptr
    float*       __restrict__ out)       // (32,56,56,256)
{
    constexpr int QKS = 40;    // q/k row stride (el); 80B
    constexpr int VTS = 72;    // vt row stride; 144B
    constexpr int PS  = 72;    // P row stride; 144B
    constexpr int OS  = 264;   // s_o row stride; 528B
    constexpr int WVSZ = 6224; // per-wave scratch: q(1960)+k(1960)+vt(2304); p aliases q+k

    __shared__ alignas(16) __hip_bfloat16 s_wv[4 * WVSZ];  // 49792 B
    __shared__ alignas(16) __hip_bfloat16 s_o[NTOK * OS];  // 25872 B
    __shared__ int s_off[NTOK];
    __shared__ int s_reg[NTOK];

    const int tid  = threadIdx.x;
    const int wave = tid >> 6;
    const int lane = tid & 63;
    const int quad = lane >> 4;
    const int l16  = lane & 15;

    const int wid  = blockIdx.x;
    const int b    = wid >> 6;
    const int wIdx = wid & 63;
    const int wh   = wIdx >> 3;
    const int wwi  = wIdx & 7;

    if (tid < NTOK) {
        int r = tid / 7, c = tid - r * 7;
        int hs = wh * 7 + r, ws = wwi * 7 + c;
        int hg = hs + 3; if (hg >= 56) hg -= 56;
        int wg = ws + 3; if (wg >= 56) wg -= 56;
        s_off[tid] = ((b * 56 + hg) * 56 + wg) * DIM_;
        int rh = (hs < 49) ? 0 : ((hs < 53) ? 1 : 2);
        int rw = (ws < 49) ? 0 : ((ws < 53) ? 1 : 2);
        s_reg[tid] = rh * 3 + rw;
    }

    __hip_bfloat16* wq  = s_wv + wave * WVSZ;
    __hip_bfloat16* wk  = wq + NTOK * QKS;        // +1960
    __hip_bfloat16* wvt = wq + 2 * NTOK * QKS;    // +3920
    __hip_bfloat16* wp  = wq;                     // aliases q+k (3528 <= 3920)

    // zero vt padding cols [49,64) once (heads only write cols <49)
    for (int i = lane; i < 32 * 15; i += 64) {
        int f = i / 15, kk = 49 + (i % 15);
        wvt[f * VTS + kk] = __float2bfloat16(0.0f);
    }
    __syncthreads();   // barrier 1: s_off/s_reg visible

    const float qscale = 0.17677669529663687f;  // 1/sqrt(32)

    for (int hp = 0; hp < 2; ++hp) {
        const int h = wave * 2 + hp;
        LGKM_WAIT();   // prior head's PV frag reads done before q/vt overwrite

        // ---- QKV: q,k,v(49x32 each) = x_win @ W^T (+bias), wave-private ----
        for (int mh = 0; mh < 2; ++mh) {
            const int mbase = mh * 32;
            v8s at[2][8];
            #pragma unroll
            for (int sub = 0; sub < 2; ++sub) {
                int tok = mbase + sub * 16 + l16;
                const float* xr = (tok < NTOK) ? (x + s_off[tok]) : nullptr;
                #pragma unroll
                for (int ks = 0; ks < 8; ++ks)
                    at[sub][ks] = xr ? cvt8(xr + ks * 32 + quad * 8) : zero_v8s();
            }
            #pragma unroll
            for (int t = 0; t < 6; ++t) {
                int mat = t >> 1, ntile = t & 1;
                int nout = mat * 256 + h * 32 + ntile * 16 + l16;
                const __hip_bfloat16* wrow = wsQ + nout * DIM_;
                v4f a0 = {0.f, 0.f, 0.f, 0.f}, a1 = {0.f, 0.f, 0.f, 0.f};
                #pragma unroll
                for (int ks = 0; ks < 8; ++ks) {
                    v8s bfr = *(const v8s*)(wrow + ks * 32 + quad * 8);
                    a0 = MFMA16(at[0][ks], bfr, a0, 0, 0, 0);
                    a1 = MFMA16(at[1][ks], bfr, a1, 0, 0, 0);
                }
                float bias  = qkvB[nout];
                float scale = (mat == 0) ? qscale : 1.0f;
                #pragma unroll
                for (int sub = 0; sub < 2; ++sub) {
                    v4f acc = sub ? a1 : a0;
                    #pragma unroll
                    for (int rg = 0; rg < 4; ++rg) {
                        int row = mbase + sub * 16 + quad * 4 + rg;
                        if (row < NTOK) {
                            float val = (acc[rg] + bias) * scale;
                            int col = ntile * 16 + l16;
                            __hip_bfloat16 bv = __float2bfloat16(val);
                            if (mat == 0)      wq[row * QKS + col] = bv;
                            else if (mat == 1) wk[row * QKS + col] = bv;
                            else               wvt[col * VTS + row] = bv;  // transposed
                        }
                    }
                }
            }
        }
        LGKM_WAIT();  // qkv writes landed

        // ---- S = q k^T (+bias+mask), softmax -> P (whole 49x49 per wave) ----
        v8s qa[4], kb[4];
        #pragma unroll
        for (int i = 0; i < 4; ++i) {
            qa[i] = lds_frag(wq, i * 16 + l16, QKS, quad * 8, NTOK);
            kb[i] = lds_frag(wk, i * 16 + l16, QKS, quad * 8, NTOK);
        }
        int regc[4];
        #pragma unroll
        for (int nt = 0; nt < 4; ++nt) {
            int col = nt * 16 + l16;
            regc[nt] = (col < NTOK) ? s_reg[col] : -1;
        }
        LGKM_WAIT();  // frags in regs before p overwrites q/k region
        const float* tabh = biasTab ? (biasTab + h * 2401) : nullptr;
        #pragma unroll
        for (int mtile = 0; mtile < 4; ++mtile) {
            v4f sa[4];
            #pragma unroll
            for (int nt = 0; nt < 4; ++nt) {
                v4f z = {0.f, 0.f, 0.f, 0.f};
                sa[nt] = MFMA16(qa[mtile], kb[nt], z, 0, 0, 0);
            }
            #pragma unroll
            for (int rg = 0; rg < 4; ++rg) {
                int row = mtile * 16 + quad * 4 + rg;
                bool rok = row < NTOK;
                int rr = rok ? s_reg[row] : -2;
                float v[4];
                float rmax = -1e30f;
                #pragma unroll
                for (int nt = 0; nt < 4; ++nt) {
                    int col = nt * 16 + l16;
                    float s = -1e30f;
                    if (rok && col < NTOK) {
                        float bv = tabh ? tabh[row * 49 + col]
                                        : rbt[rpi[row * 49 + col] * NH_ + h];
                        s = sa[nt][rg] + bv;
                        if (rr != regc[nt]) s -= 100.0f;
                    }
                    v[nt] = s;
                    rmax = fmaxf(rmax, s);
                }
                #pragma unroll
                for (int mm = 8; mm >= 1; mm >>= 1)
                    rmax = fmaxf(rmax, __shfl_xor(rmax, mm, 64));
                float rsum = 0.f;
                #pragma unroll
                for (int nt = 0; nt < 4; ++nt) {
                    float e = (v[nt] <= -1e29f) ? 0.f : __expf(v[nt] - rmax);
                    v[nt] = e;
                    rsum += e;
                }
                #pragma unroll
                for (int mm = 8; mm >= 1; mm >>= 1)
                    rsum += __shfl_xor(rsum, mm, 64);
                if (rok) {
                    float inv = 1.0f / rsum;
                    #pragma unroll
                    for (int nt = 0; nt < 4; ++nt)
                        wp[row * PS + nt * 16 + l16] = __float2bfloat16(v[nt] * inv);
                }
            }
        }
        LGKM_WAIT();  // p writes landed

        // ---- PV: oh(49x32) = P @ v -> s_o columns [h*32, h*32+32) ----
        v8s pb[2][2];
        #pragma unroll
        for (int nt = 0; nt < 2; ++nt)
            #pragma unroll
            for (int ks = 0; ks < 2; ++ks)
                pb[nt][ks] = *(const v8s*)(wvt + (nt * 16 + l16) * VTS + ks * 32 + quad * 8);
        #pragma unroll
        for (int mtile = 0; mtile < 4; ++mtile) {
            v8s pa0 = lds_frag(wp, mtile * 16 + l16, PS, quad * 8, NTOK);
            v8s pa1 = lds_frag(wp, mtile * 16 + l16, PS, 32 + quad * 8, NTOK);
            #pragma unroll
            for (int nt = 0; nt < 2; ++nt) {
                v4f z = {0.f, 0.f, 0.f, 0.f};
                v4f acc = MFMA16(pa0, pb[nt][0], z, 0, 0, 0);
                acc = MFMA16(pa1, pb[nt][1], acc, 0, 0, 0);
                #pragma unroll
                for (int rg = 0; rg < 4; ++rg) {
                    int row = mtile * 16 + quad * 4 + rg;
                    if (row < NTOK)
                        s_o[row * OS + h * 32 + nt * 16 + l16] = __float2bfloat16(acc[rg]);
                }
            }
        }
    }
    __syncthreads();   // barrier 2: s_o complete across waves

    // ---- proj: out = s_o @ projW^T + projB; wave w owns row-tile w ----
    {
        int m0 = wave * 16;
        v8s af[8];
        #pragma unroll
        for (int ks = 0; ks < 8; ++ks)
            af[ks] = lds_frag(s_o, m0 + l16, OS, ks * 32 + quad * 8, NTOK);
        #pragma unroll
        for (int t = 0; t < 16; ++t) {
            const __hip_bfloat16* wrow = wsP + (t * 16 + l16) * DIM_;
            v4f acc = {0.f, 0.f, 0.f, 0.f};
            #pragma unroll
            for (int ks = 0; ks < 8; ++ks) {
                v8s bfr = *(const v8s*)(wrow + ks * 32 + quad * 8);
                acc = MFMA16(af[ks], bfr, acc, 0, 0, 0);
            }
            float pbv = projB[t * 16 + l16];
            #pragma unroll
            for (int rg = 0; rg < 4; ++rg) {
                int row = m0 + quad * 4 + rg;
                if (row < NTOK)
                    out[s_off[row] + t * 16 + l16] = acc[rg] + pbv;
            }
        }
    }
}

extern "C" void kernel_launch(void* const* d_in, const int* in_sizes, int n_in,
                              void* d_out, int out_size, void* d_ws, size_t ws_size,
                              hipStream_t stream) {
    const float* x     = (const float*)d_in[0];
    const float* qkvW  = (const float*)d_in[1];
    const float* qkvB  = (const float*)d_in[2];
    const float* projW = (const float*)d_in[3];
    const float* projB = (const float*)d_in[4];
    const float* rbt   = (const float*)d_in[5];
    const int*   rpi   = (const int*)d_in[6];
    float* o = (float*)d_out;

    __hip_bfloat16* wsQ = (__hip_bfloat16*)d_ws;
    __hip_bfloat16* wsP = wsQ + NQKV;
    float* tab = (float*)((char*)d_ws + (size_t)(NQKV + NPRJ) * 2);
    size_t need = (size_t)(NQKV + NPRJ) * 2 + (size_t)NTAB * 4;
    int doTab = (ws_size >= need) ? 1 : 0;
    const float* tabArg = doTab ? tab : nullptr;

    int prepN = NQKV + NPRJ + NTAB;
    prep_kernel<<<(prepN + 255) / 256, 256, 0, stream>>>(qkvW, projW, rbt, rpi,
                                                         wsQ, wsP, tab, doTab);
    swin_attn_kernel<<<2048, 256, 0, stream>>>(x, qkvB, projB, rbt, rpi,
                                               wsQ, wsP, tabArg, o);
}

// Round 4
// 497.920 us; speedup vs baseline: 1.7273x; 1.3736x over previous
//
#include <hip/hip_runtime.h>
#include <hip/hip_bf16.h>

// Shifted-window attention (Swin), B=32 H=W=56 C=256 NH=8 hd=32 WS=7 SHIFT=3.
// fp32 in/out; bf16 MFMA compute.
//
// Big-workspace path (ws_size >= ~162 MB): 4 kernels
//   prep:  weights fp32->bf16; bias+mask table tab4[4 classes][8 heads][49][49] fp32
//   qkv:   per-window QKV GEMM -> Q (scaled), K row-major [win][h][49][32] bf16,
//          VT transposed [win][h][32][56] bf16 (cols 49..55 zeroed)
//   attn:  one wave per (window, head); q/k/vt frags direct from global; softmax
//          via tab4; P through per-wave LDS; oh overwrites the q slot
//   proj:  per-window GEMM oh @ projW^T + bias, fp32 scatter with reverse shift
// Fallback (small ws): round-3 fused kernel (verbatim).

#define NTOK 49
#define DIM_ 256
#define NH_  8
#define NQKV 196608          // 768*256
#define NPRJ 65536           // 256*256
#define NTAB1 19208          // 8*49*49
#define NTAB4 (4 * NTAB1)    // 76832

// ---- workspace layout (bytes) ----
#define WSP_B  393216ull                       // after wsQ (NQKV*2)
#define TAB_B  524288ull                       // after wsP (NPRJ*2)
#define Q_B    831744ull                       // after tab4 (NTAB4*4), 256B-aligned
#define QK_EL  25690112                        // 2048*8*49*32
#define Q_BYTES 51380224ull
#define K_B    (Q_B + Q_BYTES)                 // 52,211,968
#define VT_B   (K_B + Q_BYTES)                 // 103,592,192
#define VT_BYTES 58720256ull                   // 2048*8*32*56*2
#define NEED_BIG (VT_B + VT_BYTES)             // 162,312,448
#define NEED_TAB (TAB_B + (unsigned long long)NTAB4 * 4)   // 831,616

typedef short v8s __attribute__((ext_vector_type(8)));
typedef float v4f __attribute__((ext_vector_type(4)));

#define MFMA16 __builtin_amdgcn_mfma_f32_16x16x32_bf16
#define LGKM_WAIT() asm volatile("s_waitcnt lgkmcnt(0)" ::: "memory")

static __device__ __forceinline__ v8s zero_v8s() {
    v8s z = {0, 0, 0, 0, 0, 0, 0, 0};
    return z;
}

static __device__ __forceinline__ v8s lds_frag(const __hip_bfloat16* p, int row,
                                               int stride, int koff, int nrows) {
    if (row < nrows) return *(const v8s*)(p + row * stride + koff);
    return zero_v8s();
}

// 8 consecutive fp32 -> 8 bf16 fragment (32B-aligned source)
static __device__ __forceinline__ v8s cvt8(const float* p) {
    v4f a = *(const v4f*)p;
    v4f b = *(const v4f*)(p + 4);
    union { v8s v; __hip_bfloat16 h[8]; } r;
    r.h[0] = __float2bfloat16(a[0]); r.h[1] = __float2bfloat16(a[1]);
    r.h[2] = __float2bfloat16(a[2]); r.h[3] = __float2bfloat16(a[3]);
    r.h[4] = __float2bfloat16(b[0]); r.h[5] = __float2bfloat16(b[1]);
    r.h[6] = __float2bfloat16(b[2]); r.h[7] = __float2bfloat16(b[3]);
    return r.v;
}

// ======================= prep =======================
__global__ __launch_bounds__(256) void prep_kernel(
    const float* __restrict__ qkvW, const float* __restrict__ projW,
    const float* __restrict__ rbt, const int* __restrict__ rpi,
    __hip_bfloat16* __restrict__ wsQ, __hip_bfloat16* __restrict__ wsP,
    float* __restrict__ tab4, int doTab)
{
    int i = blockIdx.x * 256 + threadIdx.x;
    if (i < NQKV) { wsQ[i] = __float2bfloat16(qkvW[i]); return; }
    int j = i - NQKV;
    if (j < NPRJ) { wsP[j] = __float2bfloat16(projW[j]); return; }
    int t = j - NPRJ;
    if (!doTab || t >= NTAB4) return;
    int cls = t / NTAB1, rem = t - cls * NTAB1;
    int h = rem / 2401, p = rem - h * 2401;
    int row = p / 49, col = p - row * 49;
    // region id: nonzero only on edge windows (cls bit0 = h-edge, bit1 = w-edge)
    int rh = (cls & 1) ? (((row / 7) < 4) ? 1 : 2) : 0;
    int rw = (cls & 2) ? (((row % 7) < 4) ? 1 : 2) : 0;
    int ch = (cls & 1) ? (((col / 7) < 4) ? 1 : 2) : 0;
    int cw = (cls & 2) ? (((col % 7) < 4) ? 1 : 2) : 0;
    float mask = ((rh * 3 + rw) != (ch * 3 + cw)) ? -100.0f : 0.0f;
    tab4[t] = rbt[rpi[p] * NH_ + h] + mask;
}

// ======================= phase A: QKV GEMM =======================
__global__ __launch_bounds__(256) void qkv_kernel(
    const float* __restrict__ x,       // (32,56,56,256)
    const float* __restrict__ qkvB,    // (768,)
    const __hip_bfloat16* __restrict__ wsQ,  // (768,256) bf16
    __hip_bfloat16* __restrict__ Q,    // [win][h][49][32], scaled
    __hip_bfloat16* __restrict__ K,    // [win][h][49][32]
    __hip_bfloat16* __restrict__ VT)   // [win][h][32][56], cols 49..55 zero
{
    constexpr int SXS = 264;  // s_x row stride (el)
    __shared__ alignas(16) __hip_bfloat16 s_x[NTOK * SXS];   // 25,872 B

    const int tid = threadIdx.x, wave = tid >> 6, lane = tid & 63;
    const int quad = lane >> 4, l16 = lane & 15;
    const int win = blockIdx.x;
    const int b = win >> 6, wh = (win >> 3) & 7, wwi = win & 7;

    // stage window x -> bf16 LDS (shifted gather), cooperative
    for (int i = tid; i < NTOK * 64; i += 256) {
        int tok = i >> 6, f4 = (i & 63) * 4;
        int r = tok / 7, c = tok - r * 7;
        int hg = wh * 7 + r + 3; if (hg >= 56) hg -= 56;
        int wg = wwi * 7 + c + 3; if (wg >= 56) wg -= 56;
        float4 v = *(const float4*)(x + ((b * 56 + hg) * 56 + wg) * DIM_ + f4);
        __hip_bfloat16* dst = s_x + tok * SXS + f4;
        dst[0] = __float2bfloat16(v.x);
        dst[1] = __float2bfloat16(v.y);
        dst[2] = __float2bfloat16(v.z);
        dst[3] = __float2bfloat16(v.w);
    }
    // zero VT pad cols 49..55 for this window
    for (int i = tid; i < 256 * 7; i += 256) {
        int fg = i / 7, col = 49 + (i - fg * 7);
        int h = fg >> 5, feat = fg & 31;
        VT[((win * NH_ + h) * 32 + feat) * 56 + col] = __float2bfloat16(0.0f);
    }
    __syncthreads();

    const float qscale = 0.17677669529663687f;  // 1/sqrt(32)

    // wave handles 12 of 48 n-tiles; B-frags reused across 4 m-tiles
    for (int t = 0; t < 12; ++t) {
        int ntb = (wave * 12 + t) * 16;
        int nout = ntb + l16;
        const __hip_bfloat16* wrow = wsQ + nout * DIM_;
        v8s B[8];
        #pragma unroll
        for (int ks = 0; ks < 8; ++ks)
            B[ks] = *(const v8s*)(wrow + ks * 32 + quad * 8);
        float bias = qkvB[nout];
        int mat = ntb >> 8;           // 0=q 1=k 2=v (tiles never cross)
        int h = (ntb >> 5) & 7;
        int colb = ntb & 16;          // within-head col base {0,16}
        #pragma unroll
        for (int mt = 0; mt < 4; ++mt) {
            v4f acc = {0.f, 0.f, 0.f, 0.f};
            #pragma unroll
            for (int ks = 0; ks < 8; ++ks) {
                v8s a = lds_frag(s_x, mt * 16 + l16, SXS, ks * 32 + quad * 8, NTOK);
                acc = MFMA16(a, B[ks], acc, 0, 0, 0);
            }
            #pragma unroll
            for (int rg = 0; rg < 4; ++rg) {
                int tok = mt * 16 + quad * 4 + rg;
                if (tok < NTOK) {
                    float val = acc[rg] + bias;
                    if (mat == 0)
                        Q[((win * NH_ + h) * NTOK + tok) * 32 + colb + l16] =
                            __float2bfloat16(val * qscale);
                    else if (mat == 1)
                        K[((win * NH_ + h) * NTOK + tok) * 32 + colb + l16] =
                            __float2bfloat16(val);
                    else
                        VT[((win * NH_ + h) * 32 + colb + l16) * 56 + tok] =
                            __float2bfloat16(val);
                }
            }
        }
    }
}

// ======================= phase B: attention =======================
__global__ __launch_bounds__(256) void attn_kernel(
    const float* __restrict__ tab4,   // [4][8][49][49] bias+mask
    const __hip_bfloat16* __restrict__ K,
    const __hip_bfloat16* __restrict__ VT,
    __hip_bfloat16* __restrict__ Q)   // in: q; out: oh (overwrites own slot)
{
    constexpr int PS = 72;
    __shared__ alignas(16) __hip_bfloat16 s_p[4][NTOK * PS];  // 28,224 B

    const int tid = threadIdx.x, wave = tid >> 6, lane = tid & 63;
    const int quad = lane >> 4, l16 = lane & 15;
    const int id = blockIdx.x * 4 + wave;      // (window, head) unit
    const int win = id >> 3, h = id & 7;
    const int wh = (win >> 3) & 7, wwi = win & 7;
    const int cls = ((wh == 7) ? 1 : 0) | ((wwi == 7) ? 2 : 0);
    const float* tabh = tab4 + (cls * NH_ + h) * 2401;
    __hip_bfloat16* qs = Q + (win * NH_ + h) * (NTOK * 32);
    const __hip_bfloat16* ks_ = K + (win * NH_ + h) * (NTOK * 32);
    const __hip_bfloat16* vts = VT + (win * NH_ + h) * (32 * 56);
    __hip_bfloat16* wp = s_p[wave];

    // A/B fragments straight from global (rows >=49 stray into the next slot;
    // those values only feed masked columns / dead rows — always finite bf16)
    v8s qa[4], kb[4];
    #pragma unroll
    for (int mt = 0; mt < 4; ++mt) {
        int tok = mt * 16 + l16;
        qa[mt] = *(const v8s*)(qs + tok * 32 + quad * 8);
        kb[mt] = *(const v8s*)(ks_ + tok * 32 + quad * 8);
    }
    v8s pb[2][2];
    #pragma unroll
    for (int nt = 0; nt < 2; ++nt) {
        const __hip_bfloat16* vr = vts + (nt * 16 + l16) * 56;
        pb[nt][0] = *(const v8s*)(vr + quad * 8);
        pb[nt][1] = (quad == 3) ? zero_v8s() : *(const v8s*)(vr + 32 + quad * 8);
    }

    // S = q k^T + tab (bias+mask); softmax -> P (bf16) in per-wave LDS
    #pragma unroll
    for (int mtile = 0; mtile < 4; ++mtile) {
        v4f sa[4];
        #pragma unroll
        for (int nt = 0; nt < 4; ++nt) {
            v4f z = {0.f, 0.f, 0.f, 0.f};
            sa[nt] = MFMA16(qa[mtile], kb[nt], z, 0, 0, 0);
        }
        #pragma unroll
        for (int rg = 0; rg < 4; ++rg) {
            int row = mtile * 16 + quad * 4 + rg;
            bool rok = row < NTOK;
            float v[4];
            float rmax = -1e30f;
            #pragma unroll
            for (int nt = 0; nt < 4; ++nt) {
                int col = nt * 16 + l16;
                float s = -1e30f;
                if (rok && col < NTOK)
                    s = sa[nt][rg] + tabh[row * 49 + col];
                v[nt] = s;
                rmax = fmaxf(rmax, s);
            }
            #pragma unroll
            for (int mm = 8; mm >= 1; mm >>= 1)
                rmax = fmaxf(rmax, __shfl_xor(rmax, mm, 64));
            float rsum = 0.f;
            #pragma unroll
            for (int nt = 0; nt < 4; ++nt) {
                float e = (v[nt] <= -1e29f) ? 0.f : __expf(v[nt] - rmax);
                v[nt] = e;
                rsum += e;
            }
            #pragma unroll
            for (int mm = 8; mm >= 1; mm >>= 1)
                rsum += __shfl_xor(rsum, mm, 64);
            if (rok) {
                float inv = 1.0f / rsum;
                #pragma unroll
                for (int nt = 0; nt < 4; ++nt)
                    wp[row * PS + nt * 16 + l16] = __float2bfloat16(v[nt] * inv);
            }
        }
    }
    LGKM_WAIT();

    // PV: oh(49x32) = P @ v ; overwrite own q slot
    #pragma unroll
    for (int mtile = 0; mtile < 4; ++mtile) {
        v8s pa0 = lds_frag(wp, mtile * 16 + l16, PS, quad * 8, NTOK);
        v8s pa1 = lds_frag(wp, mtile * 16 + l16, PS, 32 + quad * 8, NTOK);
        #pragma unroll
        for (int nt = 0; nt < 2; ++nt) {
            v4f z = {0.f, 0.f, 0.f, 0.f};
            v4f acc = MFMA16(pa0, pb[nt][0], z, 0, 0, 0);
            acc = MFMA16(pa1, pb[nt][1], acc, 0, 0, 0);
            #pragma unroll
            for (int rg = 0; rg < 4; ++rg) {
                int tok = mtile * 16 + quad * 4 + rg;
                if (tok < NTOK)
                    qs[tok * 32 + nt * 16 + l16] = __float2bfloat16(acc[rg]);
            }
        }
    }
}

// ======================= phase C: projection =======================
__global__ __launch_bounds__(256) void proj_kernel(
    const __hip_bfloat16* __restrict__ OH,   // = Q region: [win][h][49][32]
    const __hip_bfloat16* __restrict__ wsP,  // (256,256) bf16
    const float* __restrict__ projB,         // (256,)
    float* __restrict__ out)                 // (32,56,56,256)
{
    const int tid = threadIdx.x, wave = tid >> 6, lane = tid & 63;
    const int quad = lane >> 4, l16 = lane & 15;
    const int win = blockIdx.x;
    const int b = win >> 6, wh = (win >> 3) & 7, wwi = win & 7;
    const int m0 = wave * 16;

    // A-frags: K dim = 256 = 8 head-slots of 32
    const __hip_bfloat16* ohw = OH + (size_t)win * (NH_ * NTOK * 32);
    v8s af[8];
    int tokA = m0 + l16;
    #pragma unroll
    for (int ks = 0; ks < 8; ++ks)
        af[ks] = (tokA < NTOK)
                   ? *(const v8s*)(ohw + ks * (NTOK * 32) + tokA * 32 + quad * 8)
                   : zero_v8s();

    // output offsets for this lane's 4 rows (window-reverse + roll(+3))
    int ooff[4];
    #pragma unroll
    for (int rg = 0; rg < 4; ++rg) {
        int row = m0 + quad * 4 + rg;
        if (row < NTOK) {
            int r = row / 7, c = row - r * 7;
            int hg = wh * 7 + r + 3; if (hg >= 56) hg -= 56;
            int wg = wwi * 7 + c + 3; if (wg >= 56) wg -= 56;
            ooff[rg] = ((b * 56 + hg) * 56 + wg) * DIM_;
        } else ooff[rg] = -1;
    }

    #pragma unroll
    for (int t = 0; t < 16; ++t) {
        const __hip_bfloat16* wrow = wsP + (t * 16 + l16) * DIM_;
        v4f acc = {0.f, 0.f, 0.f, 0.f};
        #pragma unroll
        for (int ks = 0; ks < 8; ++ks) {
            v8s bfr = *(const v8s*)(wrow + ks * 32 + quad * 8);
            acc = MFMA16(af[ks], bfr, acc, 0, 0, 0);
        }
        float pbv = projB[t * 16 + l16];
        #pragma unroll
        for (int rg = 0; rg < 4; ++rg)
            if (ooff[rg] >= 0)
                out[ooff[rg] + t * 16 + l16] = acc[rg] + pbv;
    }
}

// ======================= fallback: round-3 fused kernel =======================
__global__ __launch_bounds__(256, 2) void swin_attn_fused(
    const float* __restrict__ x,
    const float* __restrict__ qkvB,
    const float* __restrict__ projB,
    const float* __restrict__ rbt,
    const int*   __restrict__ rpi,
    const __hip_bfloat16* __restrict__ wsQ,
    const __hip_bfloat16* __restrict__ wsP,
    const float* __restrict__ biasTab,   // class-0 rows of tab4 (bias only) or null
    float*       __restrict__ out)
{
    constexpr int QKS = 40;
    constexpr int VTS = 72;
    constexpr int PS  = 72;
    constexpr int OS  = 264;
    constexpr int WVSZ = 6224;

    __shared__ alignas(16) __hip_bfloat16 s_wv[4 * WVSZ];
    __shared__ alignas(16) __hip_bfloat16 s_o[NTOK * OS];
    __shared__ int s_off[NTOK];
    __shared__ int s_reg[NTOK];

    const int tid  = threadIdx.x;
    const int wave = tid >> 6;
    const int lane = tid & 63;
    const int quad = lane >> 4;
    const int l16  = lane & 15;

    const int wid  = blockIdx.x;
    const int b    = wid >> 6;
    const int wIdx = wid & 63;
    const int wh   = wIdx >> 3;
    const int wwi  = wIdx & 7;

    if (tid < NTOK) {
        int r = tid / 7, c = tid - r * 7;
        int hs = wh * 7 + r, ws = wwi * 7 + c;
        int hg = hs + 3; if (hg >= 56) hg -= 56;
        int wg = ws + 3; if (wg >= 56) wg -= 56;
        s_off[tid] = ((b * 56 + hg) * 56 + wg) * DIM_;
        int rh = (hs < 49) ? 0 : ((hs < 53) ? 1 : 2);
        int rw = (ws < 49) ? 0 : ((ws < 53) ? 1 : 2);
        s_reg[tid] = rh * 3 + rw;
    }

    __hip_bfloat16* wq  = s_wv + wave * WVSZ;
    __hip_bfloat16* wk  = wq + NTOK * QKS;
    __hip_bfloat16* wvt = wq + 2 * NTOK * QKS;
    __hip_bfloat16* wp  = wq;

    for (int i = lane; i < 32 * 15; i += 64) {
        int f = i / 15, kk = 49 + (i % 15);
        wvt[f * VTS + kk] = __float2bfloat16(0.0f);
    }
    __syncthreads();

    const float qscale = 0.17677669529663687f;

    v4f pacc_unused; (void)pacc_unused;

    for (int hp = 0; hp < 2; ++hp) {
        const int h = wave * 2 + hp;
        LGKM_WAIT();

        for (int mh = 0; mh < 2; ++mh) {
            const int mbase = mh * 32;
            v8s at[2][8];
            #pragma unroll
            for (int sub = 0; sub < 2; ++sub) {
                int tok = mbase + sub * 16 + l16;
                const float* xr = (tok < NTOK) ? (x + s_off[tok]) : nullptr;
                #pragma unroll
                for (int ks = 0; ks < 8; ++ks)
                    at[sub][ks] = xr ? cvt8(xr + ks * 32 + quad * 8) : zero_v8s();
            }
            #pragma unroll
            for (int t = 0; t < 6; ++t) {
                int mat = t >> 1, ntile = t & 1;
                int nout = mat * 256 + h * 32 + ntile * 16 + l16;
                const __hip_bfloat16* wrow = wsQ + nout * DIM_;
                v4f a0 = {0.f, 0.f, 0.f, 0.f}, a1 = {0.f, 0.f, 0.f, 0.f};
                #pragma unroll
                for (int ks = 0; ks < 8; ++ks) {
                    v8s bfr = *(const v8s*)(wrow + ks * 32 + quad * 8);
                    a0 = MFMA16(at[0][ks], bfr, a0, 0, 0, 0);
                    a1 = MFMA16(at[1][ks], bfr, a1, 0, 0, 0);
                }
                float bias  = qkvB[nout];
                float scale = (mat == 0) ? qscale : 1.0f;
                #pragma unroll
                for (int sub = 0; sub < 2; ++sub) {
                    v4f acc = sub ? a1 : a0;
                    #pragma unroll
                    for (int rg = 0; rg < 4; ++rg) {
                        int row = mbase + sub * 16 + quad * 4 + rg;
                        if (row < NTOK) {
                            float val = (acc[rg] + bias) * scale;
                            int col = ntile * 16 + l16;
                            __hip_bfloat16 bv = __float2bfloat16(val);
                            if (mat == 0)      wq[row * QKS + col] = bv;
                            else if (mat == 1) wk[row * QKS + col] = bv;
                            else               wvt[col * VTS + row] = bv;
                        }
                    }
                }
            }
        }
        LGKM_WAIT();

        v8s qa[4], kb[4];
        #pragma unroll
        for (int i = 0; i < 4; ++i) {
            qa[i] = lds_frag(wq, i * 16 + l16, QKS, quad * 8, NTOK);
            kb[i] = lds_frag(wk, i * 16 + l16, QKS, quad * 8, NTOK);
        }
        int regc[4];
        #pragma unroll
        for (int nt = 0; nt < 4; ++nt) {
            int col = nt * 16 + l16;
            regc[nt] = (col < NTOK) ? s_reg[col] : -1;
        }
        LGKM_WAIT();
        const float* tabh = biasTab ? (biasTab + h * 2401) : nullptr;
        #pragma unroll
        for (int mtile = 0; mtile < 4; ++mtile) {
            v4f sa[4];
            #pragma unroll
            for (int nt = 0; nt < 4; ++nt) {
                v4f z = {0.f, 0.f, 0.f, 0.f};
                sa[nt] = MFMA16(qa[mtile], kb[nt], z, 0, 0, 0);
            }
            #pragma unroll
            for (int rg = 0; rg < 4; ++rg) {
                int row = mtile * 16 + quad * 4 + rg;
                bool rok = row < NTOK;
                int rr = rok ? s_reg[row] : -2;
                float v[4];
                float rmax = -1e30f;
                #pragma unroll
                for (int nt = 0; nt < 4; ++nt) {
                    int col = nt * 16 + l16;
                    float s = -1e30f;
                    if (rok && col < NTOK) {
                        float bv = tabh ? tabh[row * 49 + col]
                                        : rbt[rpi[row * 49 + col] * NH_ + h];
                        s = sa[nt][rg] + bv;
                        if (rr != regc[nt]) s -= 100.0f;
                    }
                    v[nt] = s;
                    rmax = fmaxf(rmax, s);
                }
                #pragma unroll
                for (int mm = 8; mm >= 1; mm >>= 1)
                    rmax = fmaxf(rmax, __shfl_xor(rmax, mm, 64));
                float rsum = 0.f;
                #pragma unroll
                for (int nt = 0; nt < 4; ++nt) {
                    float e = (v[nt] <= -1e29f) ? 0.f : __expf(v[nt] - rmax);
                    v[nt] = e;
                    rsum += e;
                }
                #pragma unroll
                for (int mm = 8; mm >= 1; mm >>= 1)
                    rsum += __shfl_xor(rsum, mm, 64);
                if (rok) {
                    float inv = 1.0f / rsum;
                    #pragma unroll
                    for (int nt = 0; nt < 4; ++nt)
                        wp[row * PS + nt * 16 + l16] = __float2bfloat16(v[nt] * inv);
                }
            }
        }
        LGKM_WAIT();

        v8s pb[2][2];
        #pragma unroll
        for (int nt = 0; nt < 2; ++nt)
            #pragma unroll
            for (int ks = 0; ks < 2; ++ks)
                pb[nt][ks] = *(const v8s*)(wvt + (nt * 16 + l16) * VTS + ks * 32 + quad * 8);
        #pragma unroll
        for (int mtile = 0; mtile < 4; ++mtile) {
            v8s pa0 = lds_frag(wp, mtile * 16 + l16, PS, quad * 8, NTOK);
            v8s pa1 = lds_frag(wp, mtile * 16 + l16, PS, 32 + quad * 8, NTOK);
            #pragma unroll
            for (int nt = 0; nt < 2; ++nt) {
                v4f z = {0.f, 0.f, 0.f, 0.f};
                v4f acc = MFMA16(pa0, pb[nt][0], z, 0, 0, 0);
                acc = MFMA16(pa1, pb[nt][1], acc, 0, 0, 0);
                #pragma unroll
                for (int rg = 0; rg < 4; ++rg) {
                    int row = mtile * 16 + quad * 4 + rg;
                    if (row < NTOK)
                        s_o[row * OS + h * 32 + nt * 16 + l16] = __float2bfloat16(acc[rg]);
                }
            }
        }
    }
    __syncthreads();

    {
        int m0 = wave * 16;
        v8s af[8];
        #pragma unroll
        for (int ks = 0; ks < 8; ++ks)
            af[ks] = lds_frag(s_o, m0 + l16, OS, ks * 32 + quad * 8, NTOK);
        #pragma unroll
        for (int t = 0; t < 16; ++t) {
            const __hip_bfloat16* wrow = wsP + (t * 16 + l16) * DIM_;
            v4f acc = {0.f, 0.f, 0.f, 0.f};
            #pragma unroll
            for (int ks = 0; ks < 8; ++ks) {
                v8s bfr = *(const v8s*)(wrow + ks * 32 + quad * 8);
                acc = MFMA16(af[ks], bfr, acc, 0, 0, 0);
            }
            float pbv = projB[t * 16 + l16];
            #pragma unroll
            for (int rg = 0; rg < 4; ++rg) {
                int row = m0 + quad * 4 + rg;
                if (row < NTOK)
                    out[s_off[row] + t * 16 + l16] = acc[rg] + pbv;
            }
        }
    }
}

extern "C" void kernel_launch(void* const* d_in, const int* in_sizes, int n_in,
                              void* d_out, int out_size, void* d_ws, size_t ws_size,
                              hipStream_t stream) {
    const float* x     = (const float*)d_in[0];
    const float* qkvW  = (const float*)d_in[1];
    const float* qkvB  = (const float*)d_in[2];
    const float* projW = (const float*)d_in[3];
    const float* projB = (const float*)d_in[4];
    const float* rbt   = (const float*)d_in[5];
    const int*   rpi   = (const int*)d_in[6];
    float* o = (float*)d_out;

    __hip_bfloat16* wsQ = (__hip_bfloat16*)d_ws;
    __hip_bfloat16* wsP = (__hip_bfloat16*)((char*)d_ws + WSP_B);
    float* tab4         = (float*)((char*)d_ws + TAB_B);
    __hip_bfloat16* Q   = (__hip_bfloat16*)((char*)d_ws + Q_B);
    __hip_bfloat16* K   = (__hip_bfloat16*)((char*)d_ws + K_B);
    __hip_bfloat16* VT  = (__hip_bfloat16*)((char*)d_ws + VT_B);

    const int prepBlocks = (NQKV + NPRJ + NTAB4 + 255) / 256;

    if (ws_size >= NEED_BIG) {
        prep_kernel<<<prepBlocks, 256, 0, stream>>>(qkvW, projW, rbt, rpi,
                                                    wsQ, wsP, tab4, 1);
        qkv_kernel<<<2048, 256, 0, stream>>>(x, qkvB, wsQ, Q, K, VT);
        attn_kernel<<<4096, 256, 0, stream>>>(tab4, K, VT, Q);
        proj_kernel<<<2048, 256, 0, stream>>>(Q, wsP, projB, o);
    } else {
        int doTab = (ws_size >= NEED_TAB) ? 1 : 0;
        prep_kernel<<<prepBlocks, 256, 0, stream>>>(qkvW, projW, rbt, rpi,
                                                    wsQ, wsP, tab4, doTab);
        swin_attn_fused<<<2048, 256, 0, stream>>>(x, qkvB, projB, rbt, rpi,
                                                  wsQ, wsP, doTab ? tab4 : nullptr, o);
    }
}